// Round 8
// baseline (223.492 us; speedup 1.0000x reference)
//
#include <hip/hip_runtime.h>

// Problem constants (from reference)
#define N1C 50000
#define N2C 50000
#define NNC 16
#define NIC 64
#define NDC 128
#define QB  8        // queries per block
#define MR  128      // QB*NN rows per block
#define FELEMS (N1C * NIC)   // 3.2M elements per feature array

typedef __bf16 bf16x8 __attribute__((ext_vector_type(8)));
typedef float f32x4 __attribute__((ext_vector_type(4)));
typedef unsigned u32x4 __attribute__((ext_vector_type(4)));

#if defined(__has_builtin)
#if __has_builtin(__builtin_amdgcn_cvt_pk_bf16_f32)
#define HAVE_PK_BF16 1
#endif
#endif

#ifdef HAVE_PK_BF16
typedef __bf16 bf16x2 __attribute__((ext_vector_type(2)));
static __device__ __forceinline__ unsigned int pkbf(float a, float b) {
    bf16x2 r = __builtin_amdgcn_cvt_pk_bf16_f32(a, b);
    return __builtin_bit_cast(unsigned int, r);
}
#else
static __device__ __forceinline__ unsigned short f2bf_sw(float f) {
    unsigned int u = __builtin_bit_cast(unsigned int, f);
    u += 0x7fffu + ((u >> 16) & 1u);
    return (unsigned short)(u >> 16);
}
static __device__ __forceinline__ unsigned int pkbf(float a, float b) {
    return (unsigned int)f2bf_sw(a) | ((unsigned int)f2bf_sw(b) << 16);
}
#endif

static __device__ __forceinline__ float elu(float x) {
    return x > 0.f ? x : __expf(x) - 1.f;
}

// ---- prep 1: W^T bf16 images (row-major [d][k], stride 128): wsW[m*16384 + d*128 + k] = bf16(W[k][d]) ----
__global__ void prep_w(const float* __restrict__ W1, const float* __restrict__ W2,
                       unsigned short* __restrict__ wsW) {
    const int idx = blockIdx.x * 256 + threadIdx.x;   // 0 .. 32767
    const int m   = idx >> 14;
    const int o   = idx & 16383;
    const int d   = o >> 7;
    const int k   = o & 127;
    const float* W = m ? W2 : W1;
    wsW[idx] = (unsigned short)pkbf(W[(size_t)k * NDC + d], 0.f);
}

// ---- prep 2: features1/features2 -> bf16 (8 floats per thread) ----
__global__ void prep_f(const float* __restrict__ f1, const float* __restrict__ f2,
                       unsigned short* __restrict__ dst) {   // dst = f1b (f2b follows)
    const int g = blockIdx.x * 256 + threadIdx.x;            // 0 .. 799999
    const size_t base = (size_t)g * 8;
    const float* src = (base < FELEMS) ? (f1 + base) : (f2 + base - FELEMS);
    const float4 v0 = *(const float4*)src;
    const float4 v1 = *(const float4*)(src + 4);
    uint4 o;
    o.x = pkbf(v0.x, v0.y);
    o.y = pkbf(v0.z, v0.w);
    o.z = pkbf(v1.x, v1.y);
    o.w = pkbf(v1.z, v1.w);
    *(uint4*)(dst + base) = o;
}

// ADD-swizzle: logical 16B-chunk (row r, chunk c), o = r*16+c -> phys uint4 index.
// B-frag reads then hit bank-group (c_logical + l16) & 7 -> uniform over lanes (conflict-free);
// XOR swizzle cancelled against the c = base ^ l16 access pattern (R7: 4x read inflation).
static __device__ __forceinline__ int swz(int o) {
    return (o & ~15) | ((o + (o >> 4)) & 15);
}

__global__ __launch_bounds__(256, 4)
void fused_knn_mlp(const unsigned short* __restrict__ f1b,
                   const unsigned short* __restrict__ f2b,
                   const float* __restrict__ x1,
                   const float* __restrict__ x2,
                   const int*   __restrict__ topk,
                   const float* __restrict__ b1,
                   const float* __restrict__ b2,
                   const float* __restrict__ radius,
                   const unsigned short* __restrict__ wsW,
                   float* __restrict__ out)
{
    __shared__ uint4 sW[2048];   // 32 KB: W1^T, restaged to W2^T mid-kernel (ADD-swizzled)

    const int tid  = threadIdx.x;
    const int blk  = blockIdx.x;
    const int lane = tid & 63;
    const int wave = tid >> 6;
    const int quad = lane >> 4;
    const int l16  = lane & 15;
    const int rloc = wave * 32 + l16;   // this lane's row0 within the group (row1 = +16)

    // ---- this lane's two rows ----
    const int idx0 = topk[blk * MR + rloc];
    const int idx1 = topk[blk * MR + rloc + 16];
    const int q0   = blk * QB + wave * 2;
    const int q1   = q0 + 1;

    // ---- X B-frags: direct global gather (issued ASAP, overlap W staging) ----
    // k 0..63 = features2[idx] (neighbor), k 64..127 = features1[q] (self) — reference concat order.
    uint4 xf0[4], xf1[4];
    #pragma unroll
    for (int ks = 0; ks < 2; ++ks) {
        xf0[ks] = *(const uint4*)(f2b + (size_t)idx0 * NIC + ks * 32 + quad * 8);
        xf1[ks] = *(const uint4*)(f2b + (size_t)idx1 * NIC + ks * 32 + quad * 8);
        xf0[ks + 2] = *(const uint4*)(f1b + (size_t)q0 * NIC + ks * 32 + quad * 8);
        xf1[ks + 2] = *(const uint4*)(f1b + (size_t)q1 * NIC + ks * 32 + quad * 8);
    }

    // ---- stage W1^T into LDS (swizzled; 8 uint4/thread) ----
    {
        const uint4* wp = (const uint4*)wsW;
        #pragma unroll
        for (int it = 0; it < 8; ++it) {
            const int o = it * 256 + tid;
            sW[swz(o)] = wp[o];
        }
    }

    // ---- distance weights for rows r0, r1 (redundant across quads; shuffled later) ----
    float wg0, wg1;
    {
        const float rr = radius[0];
        const float inv2r2 = 1.f / (2.f * rr * rr);
        const float dx0 = x2[idx0 * 3 + 0] - x1[q0 * 3 + 0];
        const float dy0 = x2[idx0 * 3 + 1] - x1[q0 * 3 + 1];
        const float dz0 = x2[idx0 * 3 + 2] - x1[q0 * 3 + 2];
        const float dx1 = x2[idx1 * 3 + 0] - x1[q1 * 3 + 0];
        const float dy1 = x2[idx1 * 3 + 1] - x1[q1 * 3 + 1];
        const float dz1 = x2[idx1 * 3 + 2] - x1[q1 * 3 + 2];
        wg0 = (idx0 == 0) ? 0.f : __expf(-(dx0 * dx0 + dy0 * dy0 + dz0 * dz0) * inv2r2);
        wg1 = (idx1 == 0) ? 0.f : __expf(-(dx1 * dx1 + dy1 * dy1 + dz1 * dz1) * inv2r2);
    }

    __syncthreads();   // W1 visible

    // ---- layer 1 (swapped): D1[d1][r] = sum_k W1T[d1][k] * X[r][k] ----
    // A = W1T frag (lane l16 <-> d1 = mt*16+l16, k = ks*32+quad*8), B = xf (lane l16 <-> row)
    f32x4 acc[8][2];
    #pragma unroll
    for (int mt = 0; mt < 8; ++mt) {
        acc[mt][0] = (f32x4){0.f, 0.f, 0.f, 0.f};
        acc[mt][1] = acc[mt][0];
    }
    #pragma unroll
    for (int ks = 0; ks < 4; ++ks) {
        const bf16x8 x0 = __builtin_bit_cast(bf16x8, xf0[ks]);
        const bf16x8 x1v = __builtin_bit_cast(bf16x8, xf1[ks]);
        #pragma unroll
        for (int mt = 0; mt < 8; ++mt) {
            // logical (row = mt*16+l16, chunk = ks*4+quad) -> phys chunk (ks*4+quad + l16) & 15
            const bf16x8 a = *(const bf16x8*)&sW[(mt * 16 + l16) * 16 + ((ks * 4 + quad + l16) & 15)];
            acc[mt][0] = __builtin_amdgcn_mfma_f32_16x16x32_bf16(a, x0, acc[mt][0], 0, 0, 0);
            acc[mt][1] = __builtin_amdgcn_mfma_f32_16x16x32_bf16(a, x1v, acc[mt][1], 0, 0, 0);
        }
    }

    __syncthreads();   // all waves done reading W1

    // ---- issue W2 image loads (short-lived regs; latency hidden by P pack below) ----
    uint4 w2t[8];
    {
        const uint4* wp2 = ((const uint4*)wsW) + 2048;
        #pragma unroll
        for (int it = 0; it < 8; ++it)
            w2t[it] = wp2[it * 256 + tid];
    }

    // ---- elu + bias + pack h1^T into P (register-only; overlaps w2t loads) ----
    // Lane (quad,l16) holds h1[r = wave*32+nt*16+l16][d = mt*16+quad*4+reg]
    unsigned P[8][2][2];
    #pragma unroll
    for (int mt = 0; mt < 8; ++mt) {
        const float4 b1v = *(const float4*)(b1 + mt * 16 + quad * 4);
        #pragma unroll
        for (int nt = 0; nt < 2; ++nt) {
            P[mt][nt][0] = pkbf(elu(acc[mt][nt][0] + b1v.x), elu(acc[mt][nt][1] + b1v.y));
            P[mt][nt][1] = pkbf(elu(acc[mt][nt][2] + b1v.z), elu(acc[mt][nt][3] + b1v.w));
        }
    }

    // ---- restage W2 into LDS ----
    #pragma unroll
    for (int it = 0; it < 8; ++it)
        sW[swz(it * 256 + tid)] = w2t[it];
    __syncthreads();   // W2 visible

    // ---- layer 2: D2[r][d2] = sum_d h1[r][d] * W2T[d2][d] ----
    // A-frags from P via cross-quad shuffles; B = W2T from LDS.
    f32x4 acc2[2][8];
    #pragma unroll
    for (int nt2 = 0; nt2 < 8; ++nt2) {
        acc2[0][nt2] = (f32x4){0.f, 0.f, 0.f, 0.f};
        acc2[1][nt2] = acc2[0][nt2];
    }
    #pragma unroll
    for (int ks = 0; ks < 4; ++ks) {
        u32x4 a2[2];
        #pragma unroll
        for (int mt2 = 0; mt2 < 2; ++mt2) {
            #pragma unroll
            for (int u = 0; u < 4; ++u) {
                const int src = (((quad * 2) + (u >> 1)) & 3) * 16 + l16;
                const unsigned lo = __shfl(P[2 * ks][mt2][u & 1], src, 64);
                const unsigned hi = __shfl(P[2 * ks + 1][mt2][u & 1], src, 64);
                a2[mt2][u] = (quad & 2) ? hi : lo;
            }
        }
        const bf16x8 af0 = __builtin_bit_cast(bf16x8, a2[0]);
        const bf16x8 af1 = __builtin_bit_cast(bf16x8, a2[1]);
        #pragma unroll
        for (int nt2 = 0; nt2 < 8; ++nt2) {
            const bf16x8 b = *(const bf16x8*)&sW[(nt2 * 16 + l16) * 16 + ((ks * 4 + quad + l16) & 15)];
            acc2[0][nt2] = __builtin_amdgcn_mfma_f32_16x16x32_bf16(af0, b, acc2[0][nt2], 0, 0, 0);
            acc2[1][nt2] = __builtin_amdgcn_mfma_f32_16x16x32_bf16(af1, b, acc2[1][nt2], 0, 0, 0);
        }
    }

    // ---- epilogue: out[q][d2] = sum_rows w * elu(h2 + b2) ----
    // acc2 row = quad*4+reg (neighbor within query), col = l16 (d2 within nt2 tile)
    float wk0[4], wk1[4];
    #pragma unroll
    for (int reg = 0; reg < 4; ++reg) {
        const int src = (lane & 48) | (quad * 4 + reg);
        wk0[reg] = __shfl(wg0, src, 64);
        wk1[reg] = __shfl(wg1, src, 64);
    }
    #pragma unroll
    for (int mt2 = 0; mt2 < 2; ++mt2) {
        #pragma unroll
        for (int nt2 = 0; nt2 < 8; ++nt2) {
            const int d2 = nt2 * 16 + l16;
            const float bb = b2[d2];
            float s;
            if (mt2 == 0)
                s = elu(acc2[0][nt2][0] + bb) * wk0[0] + elu(acc2[0][nt2][1] + bb) * wk0[1]
                  + elu(acc2[0][nt2][2] + bb) * wk0[2] + elu(acc2[0][nt2][3] + bb) * wk0[3];
            else
                s = elu(acc2[1][nt2][0] + bb) * wk1[0] + elu(acc2[1][nt2][1] + bb) * wk1[1]
                  + elu(acc2[1][nt2][2] + bb) * wk1[2] + elu(acc2[1][nt2][3] + bb) * wk1[3];
            s += __shfl_xor(s, 16, 64);
            s += __shfl_xor(s, 32, 64);
            if (lane < 16) {
                out[(size_t)(blk * QB + wave * 2 + mt2) * NDC + d2] = s;
            }
        }
    }
}

extern "C" void kernel_launch(void* const* d_in, const int* in_sizes, int n_in,
                              void* d_out, int out_size, void* d_ws, size_t ws_size,
                              hipStream_t stream) {
    const float* features1 = (const float*)d_in[0];
    const float* features2 = (const float*)d_in[1];
    const float* x1        = (const float*)d_in[2];
    const float* x2        = (const float*)d_in[3];
    // d_in[4], d_in[5] = nuv1, nuv2 (unused by reference)
    const int*   topk      = (const int*)d_in[6];
    const float* W1        = (const float*)d_in[7];
    const float* b1        = (const float*)d_in[8];
    const float* W2        = (const float*)d_in[9];
    const float* b2        = (const float*)d_in[10];
    const float* radius    = (const float*)d_in[11];
    float* out = (float*)d_out;

    unsigned short* wsW = (unsigned short*)d_ws;      // 32768 shorts = 64 KB
    unsigned short* f1b = wsW + 32768;                // 3.2M shorts
    unsigned short* f2b = f1b + FELEMS;               // 3.2M shorts

    prep_w<<<dim3(128), 256, 0, stream>>>(W1, W2, wsW);
    prep_f<<<dim3(3125), 256, 0, stream>>>(features1, features2, f1b);
    fused_knn_mlp<<<dim3(N1C / QB), 256, 0, stream>>>(f1b, f2b, x1, x2, topk,
                                                      b1, b2, radius, wsW, out);
}

// Round 9
// 198.323 us; speedup vs baseline: 1.1269x; 1.1269x over previous
//
#include <hip/hip_runtime.h>

// Problem constants (from reference)
#define N1C 50000
#define N2C 50000
#define NNC 16
#define NIC 64
#define NDC 128
#define QB  8        // queries per block
#define MR  128      // QB*NN rows per block
#define FELEMS (N1C * NIC)   // 3.2M elements per feature array

typedef __bf16 bf16x8 __attribute__((ext_vector_type(8)));
typedef float f32x4 __attribute__((ext_vector_type(4)));
typedef unsigned u32x4 __attribute__((ext_vector_type(4)));

#if defined(__has_builtin)
#if __has_builtin(__builtin_amdgcn_cvt_pk_bf16_f32)
#define HAVE_PK_BF16 1
#endif
#endif

#ifdef HAVE_PK_BF16
typedef __bf16 bf16x2 __attribute__((ext_vector_type(2)));
static __device__ __forceinline__ unsigned int pkbf(float a, float b) {
    bf16x2 r = __builtin_amdgcn_cvt_pk_bf16_f32(a, b);
    return __builtin_bit_cast(unsigned int, r);
}
#else
static __device__ __forceinline__ unsigned short f2bf_sw(float f) {
    unsigned int u = __builtin_bit_cast(unsigned int, f);
    u += 0x7fffu + ((u >> 16) & 1u);
    return (unsigned short)(u >> 16);
}
static __device__ __forceinline__ unsigned int pkbf(float a, float b) {
    return (unsigned int)f2bf_sw(a) | ((unsigned int)f2bf_sw(b) << 16);
}
#endif

static __device__ __forceinline__ float elu(float x) {
    return x > 0.f ? x : __expf(x) - 1.f;
}

// Async global->LDS DMA, 16B per lane. LDS dest = wave-uniform base + lane*16.
static __device__ __forceinline__ void stage16(const uint4* gsrc_lane, uint4* ldst_base) {
#if defined(__has_builtin) && __has_builtin(__builtin_amdgcn_global_load_lds)
    __builtin_amdgcn_global_load_lds(
        (const __attribute__((address_space(1))) void*)gsrc_lane,
        (__attribute__((address_space(3))) void*)ldst_base, 16, 0, 0);
#else
    ldst_base[threadIdx.x & 63] = *gsrc_lane;
#endif
}

// ---- prep 1: W^T bf16 images in MFMA FRAGMENT ORDER ----
// chunk index ((mt*4+ks)*64 + lane), 8 shorts/chunk: W^T[d = mt*16 + (lane&15)][k = ks*32 + (lane>>4)*8 + j]
__global__ void prep_w(const float* __restrict__ W1, const float* __restrict__ W2,
                       unsigned short* __restrict__ wsW) {
    const int idx  = blockIdx.x * 256 + threadIdx.x;   // 0 .. 32767
    const int m    = idx >> 14;
    const int o    = idx & 16383;
    const int j    = o & 7;
    const int lane = (o >> 3) & 63;
    const int ksmt = o >> 9;         // mt*4 + ks
    const int ks   = ksmt & 3;
    const int mt   = ksmt >> 2;
    const int d = mt * 16 + (lane & 15);
    const int k = ks * 32 + (lane >> 4) * 8 + j;
    const float* W = m ? W2 : W1;
    wsW[idx] = (unsigned short)pkbf(W[(size_t)k * NDC + d], 0.f);
}

// ---- prep 2: features1/features2 -> bf16 (8 floats per thread) ----
__global__ void prep_f(const float* __restrict__ f1, const float* __restrict__ f2,
                       unsigned short* __restrict__ dst) {   // dst = f1b (f2b follows)
    const int g = blockIdx.x * 256 + threadIdx.x;            // 0 .. 799999
    const size_t base = (size_t)g * 8;
    const float* src = (base < FELEMS) ? (f1 + base) : (f2 + base - FELEMS);
    const float4 v0 = *(const float4*)src;
    const float4 v1 = *(const float4*)(src + 4);
    uint4 o;
    o.x = pkbf(v0.x, v0.y);
    o.y = pkbf(v0.z, v0.w);
    o.z = pkbf(v1.x, v1.y);
    o.w = pkbf(v1.z, v1.w);
    *(uint4*)(dst + base) = o;
}

__global__ __launch_bounds__(256, 4)
void fused_knn_mlp(const unsigned short* __restrict__ f1b,
                   const unsigned short* __restrict__ f2b,
                   const float* __restrict__ x1,
                   const float* __restrict__ x2,
                   const int*   __restrict__ topk,
                   const float* __restrict__ b1,
                   const float* __restrict__ b2,
                   const float* __restrict__ radius,
                   const unsigned short* __restrict__ wsW,
                   float* __restrict__ out)
{
    __shared__ uint4 sW[2048];   // 32 KB, fragment-order W1^T then restaged W2^T

    const int tid  = threadIdx.x;
    const int blk  = blockIdx.x;
    const int lane = tid & 63;
    const int wave = tid >> 6;
    const int quad = lane >> 4;
    const int l16  = lane & 15;
    const int rloc = wave * 32 + l16;   // this lane's row0 within the group (row1 = +16)

    const uint4* wp1 = (const uint4*)wsW;   // 2048 chunks (W1)
    const uint4* wp2 = wp1 + 2048;          // 2048 chunks (W2)

    // ---- W1 DMA into LDS: zero VGPRs, async (vmcnt) ----
    #pragma unroll
    for (int it = 0; it < 8; ++it) {
        const int base = wave * 512 + it * 64;
        stage16(wp1 + base + lane, sW + base);
    }

    // ---- this lane's two rows + X B-frags (direct global gather, overlaps DMA) ----
    const int idx0 = topk[blk * MR + rloc];
    const int idx1 = topk[blk * MR + rloc + 16];
    const int q0   = blk * QB + wave * 2;
    const int q1   = q0 + 1;

    // k 0..63 = features2[idx] (neighbor), k 64..127 = features1[q] (self) — reference concat order.
    uint4 xf0[4], xf1[4];
    #pragma unroll
    for (int ks = 0; ks < 2; ++ks) {
        xf0[ks] = *(const uint4*)(f2b + (size_t)idx0 * NIC + ks * 32 + quad * 8);
        xf1[ks] = *(const uint4*)(f2b + (size_t)idx1 * NIC + ks * 32 + quad * 8);
        xf0[ks + 2] = *(const uint4*)(f1b + (size_t)q0 * NIC + ks * 32 + quad * 8);
        xf1[ks + 2] = *(const uint4*)(f1b + (size_t)q1 * NIC + ks * 32 + quad * 8);
    }

    // ---- distance weights for rows r0, r1 ----
    float wg0, wg1;
    {
        const float rr = radius[0];
        const float inv2r2 = 1.f / (2.f * rr * rr);
        const float dx0 = x2[idx0 * 3 + 0] - x1[q0 * 3 + 0];
        const float dy0 = x2[idx0 * 3 + 1] - x1[q0 * 3 + 1];
        const float dz0 = x2[idx0 * 3 + 2] - x1[q0 * 3 + 2];
        const float dx1 = x2[idx1 * 3 + 0] - x1[q1 * 3 + 0];
        const float dy1 = x2[idx1 * 3 + 1] - x1[q1 * 3 + 1];
        const float dz1 = x2[idx1 * 3 + 2] - x1[q1 * 3 + 2];
        wg0 = (idx0 == 0) ? 0.f : __expf(-(dx0 * dx0 + dy0 * dy0 + dz0 * dz0) * inv2r2);
        wg1 = (idx1 == 0) ? 0.f : __expf(-(dx1 * dx1 + dy1 * dy1 + dz1 * dz1) * inv2r2);
    }

    __syncthreads();   // W1 DMA drained (vmcnt) + all waves ready

    // ---- layer 1 (swapped): D1[d1][r] = sum_k W1T[d1][k] * X[r][k] ----
    // Progressive: mt-pairs, pack to P immediately (acc slice = 16 AGPRs, not 64).
    // Lane (quad,l16) of P holds h1[r = wave*32 + nt*16 + l16][d = mt*16 + quad*4 + reg]
    unsigned P[8][2][2];
    #pragma unroll
    for (int mp = 0; mp < 4; ++mp) {
        f32x4 accp[2][2];   // [mt within pair][row tile]
        #pragma unroll
        for (int mi = 0; mi < 2; ++mi) {
            accp[mi][0] = (f32x4){0.f, 0.f, 0.f, 0.f};
            accp[mi][1] = accp[mi][0];
        }
        #pragma unroll
        for (int ks = 0; ks < 4; ++ks) {
            const bf16x8 x0  = __builtin_bit_cast(bf16x8, xf0[ks]);
            const bf16x8 x1v = __builtin_bit_cast(bf16x8, xf1[ks]);
            #pragma unroll
            for (int mi = 0; mi < 2; ++mi) {
                const int mt = mp * 2 + mi;
                const bf16x8 a = *(const bf16x8*)&sW[(mt * 4 + ks) * 64 + lane];  // frag order: offset-imm
                accp[mi][0] = __builtin_amdgcn_mfma_f32_16x16x32_bf16(a, x0,  accp[mi][0], 0, 0, 0);
                accp[mi][1] = __builtin_amdgcn_mfma_f32_16x16x32_bf16(a, x1v, accp[mi][1], 0, 0, 0);
            }
        }
        #pragma unroll
        for (int mi = 0; mi < 2; ++mi) {
            const int mt = mp * 2 + mi;
            const float4 b1v = *(const float4*)(b1 + mt * 16 + quad * 4);
            #pragma unroll
            for (int nt = 0; nt < 2; ++nt) {
                P[mt][nt][0] = pkbf(elu(accp[mi][nt][0] + b1v.x), elu(accp[mi][nt][1] + b1v.y));
                P[mt][nt][1] = pkbf(elu(accp[mi][nt][2] + b1v.z), elu(accp[mi][nt][3] + b1v.w));
            }
        }
    }

    __syncthreads();   // all waves done reading W1

    // ---- W2 DMA into LDS (async; drained by next barrier) ----
    #pragma unroll
    for (int it = 0; it < 8; ++it) {
        const int base = wave * 512 + it * 64;
        stage16(wp2 + base + lane, sW + base);
    }
    __syncthreads();   // W2 visible

    // ---- layer 2: D2[r][d2] = sum_d h1[r][d] * W2T[d2][d] ----
    // A-frags from P via cross-quad shuffles; B = W2T frags from LDS (offset-imm).
    f32x4 acc2[2][8];
    #pragma unroll
    for (int nt2 = 0; nt2 < 8; ++nt2) {
        acc2[0][nt2] = (f32x4){0.f, 0.f, 0.f, 0.f};
        acc2[1][nt2] = acc2[0][nt2];
    }
    #pragma unroll
    for (int ks = 0; ks < 4; ++ks) {
        u32x4 a2[2];
        #pragma unroll
        for (int mt2 = 0; mt2 < 2; ++mt2) {
            #pragma unroll
            for (int u = 0; u < 4; ++u) {
                const int src = (((quad * 2) + (u >> 1)) & 3) * 16 + l16;
                const unsigned lo = __shfl(P[2 * ks][mt2][u & 1], src, 64);
                const unsigned hi = __shfl(P[2 * ks + 1][mt2][u & 1], src, 64);
                a2[mt2][u] = (quad & 2) ? hi : lo;
            }
        }
        const bf16x8 af0 = __builtin_bit_cast(bf16x8, a2[0]);
        const bf16x8 af1 = __builtin_bit_cast(bf16x8, a2[1]);
        #pragma unroll
        for (int nt2 = 0; nt2 < 8; ++nt2) {
            const bf16x8 b = *(const bf16x8*)&sW[(nt2 * 4 + ks) * 64 + lane];
            acc2[0][nt2] = __builtin_amdgcn_mfma_f32_16x16x32_bf16(af0, b, acc2[0][nt2], 0, 0, 0);
            acc2[1][nt2] = __builtin_amdgcn_mfma_f32_16x16x32_bf16(af1, b, acc2[1][nt2], 0, 0, 0);
        }
    }

    // ---- epilogue: out[q][d2] = sum_rows w * elu(h2 + b2) ----
    // acc2 row = quad*4+reg (neighbor within query), col = l16 (d2 within nt2 tile)
    float wk0[4], wk1[4];
    #pragma unroll
    for (int reg = 0; reg < 4; ++reg) {
        const int src = (lane & 48) | (quad * 4 + reg);
        wk0[reg] = __shfl(wg0, src, 64);
        wk1[reg] = __shfl(wg1, src, 64);
    }
    #pragma unroll
    for (int mt2 = 0; mt2 < 2; ++mt2) {
        #pragma unroll
        for (int nt2 = 0; nt2 < 8; ++nt2) {
            const int d2 = nt2 * 16 + l16;
            const float bb = b2[d2];
            float s;
            if (mt2 == 0)
                s = elu(acc2[0][nt2][0] + bb) * wk0[0] + elu(acc2[0][nt2][1] + bb) * wk0[1]
                  + elu(acc2[0][nt2][2] + bb) * wk0[2] + elu(acc2[0][nt2][3] + bb) * wk0[3];
            else
                s = elu(acc2[1][nt2][0] + bb) * wk1[0] + elu(acc2[1][nt2][1] + bb) * wk1[1]
                  + elu(acc2[1][nt2][2] + bb) * wk1[2] + elu(acc2[1][nt2][3] + bb) * wk1[3];
            s += __shfl_xor(s, 16, 64);
            s += __shfl_xor(s, 32, 64);
            if (lane < 16) {
                out[(size_t)(blk * QB + wave * 2 + mt2) * NDC + d2] = s;
            }
        }
    }
}

extern "C" void kernel_launch(void* const* d_in, const int* in_sizes, int n_in,
                              void* d_out, int out_size, void* d_ws, size_t ws_size,
                              hipStream_t stream) {
    const float* features1 = (const float*)d_in[0];
    const float* features2 = (const float*)d_in[1];
    const float* x1        = (const float*)d_in[2];
    const float* x2        = (const float*)d_in[3];
    // d_in[4], d_in[5] = nuv1, nuv2 (unused by reference)
    const int*   topk      = (const int*)d_in[6];
    const float* W1        = (const float*)d_in[7];
    const float* b1        = (const float*)d_in[8];
    const float* W2        = (const float*)d_in[9];
    const float* b2        = (const float*)d_in[10];
    const float* radius    = (const float*)d_in[11];
    float* out = (float*)d_out;

    unsigned short* wsW = (unsigned short*)d_ws;      // 32768 shorts = 64 KB (frag-order W1,W2)
    unsigned short* f1b = wsW + 32768;                // 3.2M shorts
    unsigned short* f2b = f1b + FELEMS;               // 3.2M shorts

    prep_w<<<dim3(128), 256, 0, stream>>>(W1, W2, wsW);
    prep_f<<<dim3(3125), 256, 0, stream>>>(features1, features2, f1b);
    fused_knn_mlp<<<dim3(N1C / QB), 256, 0, stream>>>(f1b, f2b, x1, x2, topk,
                                                      b1, b2, radius, wsW, out);
}